// Round 1
// baseline (21946.375 us; speedup 1.0000x reference)
//
#include <hip/hip_runtime.h>
#include <hip/hip_bf16.h>

typedef unsigned short u16;
typedef unsigned int u32;

// Problem constants
#define NB   32      // batch
#define TSEQ 512     // L+1
#define TENC 1024
#define HD   1024    // hidden
#define G3   3072    // 3*H
#define VOC  512

__device__ __forceinline__ float b2f(u16 u) {
  union { u32 i; float f; } x; x.i = ((u32)u) << 16; return x.f;
}
__device__ __forceinline__ u16 f2b(float f) {
  union { float ff; u32 i; } x; x.ff = f;
  u32 r = x.i + 0x7fff + ((x.i >> 16) & 1);   // RNE
  return (u16)(r >> 16);
}
// flag-dispatched input load: inputs may be f32 (expected) or bf16 (hedge)
__device__ __forceinline__ float inF(const void* p, size_t i, int bf) {
  return bf ? b2f(((const u16*)p)[i]) : ((const float*)p)[i];
}
__device__ __forceinline__ void inF4(const void* p, size_t i, int bf, float* o) {
  if (bf) {
    ushort4 u = *reinterpret_cast<const ushort4*>((const u16*)p + i);
    o[0] = b2f(u.x); o[1] = b2f(u.y); o[2] = b2f(u.z); o[3] = b2f(u.w);
  } else {
    float4 v = *reinterpret_cast<const float4*>((const float*)p + i);
    o[0] = v.x; o[1] = v.y; o[2] = v.z; o[3] = v.w;
  }
}
__device__ __forceinline__ void outF(void* p, size_t i, float v, int bf) {
  if (bf) ((u16*)p)[i] = f2b(v);
  else ((float*)p)[i] = v;
}

// ---------------- dtype detect: exponent-byte histogram on emb ----------------
__global__ void k_detect(const u32* __restrict__ w, int* __restrict__ flag) {
  __shared__ int cnt;
  if (threadIdx.x == 0) cnt = 0;
  __syncthreads();
  int c = 0;
  for (int i = threadIdx.x; i < 1024; i += 256) {
    u32 e = (w[i] >> 7) & 0xFF;  // bf16-low-element exponent field / f32 mid-mantissa bits
    if (e >= 100 && e <= 126) c++;
  }
  atomicAdd(&cnt, c);
  __syncthreads();
  if (threadIdx.x == 0) flag[0] = (cnt >= 512) ? 1 : 0;
}

// ---------------- embedding gather (with SOS prepend) -> bf16 x ----------------
__global__ __launch_bounds__(256) void k_embed(
    const int* __restrict__ labels, const void* __restrict__ emb,
    u16* __restrict__ x, const int* __restrict__ flagp) {
  const int bf = flagp[0];
  const int m = blockIdx.x;            // m = b*512 + t
  const int b = m >> 9, t = m & 511;
  const int lab = (t == 0) ? 0 : labels[b * 511 + t - 1];
  const size_t src = (size_t)lab * HD;
  const size_t dst = (size_t)m * HD;
  const int k = threadIdx.x * 4;
  float v[4]; inF4(emb, src + k, bf, v);
  ushort4 o; o.x = f2b(v[0]); o.y = f2b(v[1]); o.z = f2b(v[2]); o.w = f2b(v[3]);
  *reinterpret_cast<ushort4*>(&x[dst + k]) = o;
}

// ---------------- tiled GEMM, C = act(A @ B^T + bias) ----------------
// A: bf16 ws tensor (optionally split in K: A0 then A1), B: input (flag dtype) [N][K]
#define BM 128
#define BN 64
#define BK 16

__global__ __launch_bounds__(256) void k_gemm_nt(
    const u16* __restrict__ A0, const u16* __restrict__ A1, int splitK, int K,
    const void* __restrict__ B, size_t strideB,
    const void* __restrict__ bias,
    void* __restrict__ C, int cF32, size_t strideC, int ldc,
    size_t strideA, int act, const int* __restrict__ flagp) {
  const int bf = flagp[0];
  __shared__ float a_s[BK][BM + 4];
  __shared__ float b_s[BK][BN + 4];
  const int tid = threadIdx.x;
  const size_t m0 = (size_t)blockIdx.x * BM;
  const int n0 = blockIdx.y * BN;
  const size_t bz = blockIdx.z;
  const int tm = tid & 15, tn = tid >> 4;          // 16 x 16 threads, 8x4 micro
  const int arow = tid >> 1, ak8 = (tid & 1) << 3; // A staging: 128 rows x 16k
  const int brow = tid >> 2, bk4 = (tid & 3) << 2; // B staging: 64 rows x 16k
  float acc[8][4];
#pragma unroll
  for (int i = 0; i < 8; i++)
#pragma unroll
    for (int j = 0; j < 4; j++) acc[i][j] = 0.f;

  for (int k0 = 0; k0 < K; k0 += BK) {
    {  // stage A (bf16)
      int kk = k0 + ak8;
      const u16* Ap = A0; int lda = splitK;
      if (kk >= splitK) { Ap = A1; lda = K - splitK; kk -= splitK; }
      const u16* ap = Ap + strideA * bz + (m0 + arow) * (size_t)lda + kk;
      ushort4 u0 = reinterpret_cast<const ushort4*>(ap)[0];
      ushort4 u1 = reinterpret_cast<const ushort4*>(ap)[1];
      a_s[ak8 + 0][arow] = b2f(u0.x); a_s[ak8 + 1][arow] = b2f(u0.y);
      a_s[ak8 + 2][arow] = b2f(u0.z); a_s[ak8 + 3][arow] = b2f(u0.w);
      a_s[ak8 + 4][arow] = b2f(u1.x); a_s[ak8 + 5][arow] = b2f(u1.y);
      a_s[ak8 + 6][arow] = b2f(u1.z); a_s[ak8 + 7][arow] = b2f(u1.w);
    }
    {  // stage B (flag dtype), NT: B[n][k]
      float v[4];
      inF4(B, strideB * bz + (size_t)(n0 + brow) * K + (k0 + bk4), bf, v);
      b_s[bk4 + 0][brow] = v[0]; b_s[bk4 + 1][brow] = v[1];
      b_s[bk4 + 2][brow] = v[2]; b_s[bk4 + 3][brow] = v[3];
    }
    __syncthreads();
#pragma unroll
    for (int k = 0; k < BK; k++) {
      const float4 av0 = *reinterpret_cast<const float4*>(&a_s[k][tm * 8]);
      const float4 av1 = *reinterpret_cast<const float4*>(&a_s[k][tm * 8 + 4]);
      const float4 bv = *reinterpret_cast<const float4*>(&b_s[k][tn * 4]);
      const float a8[8] = {av0.x, av0.y, av0.z, av0.w, av1.x, av1.y, av1.z, av1.w};
      const float b4[4] = {bv.x, bv.y, bv.z, bv.w};
#pragma unroll
      for (int i = 0; i < 8; i++)
#pragma unroll
        for (int j = 0; j < 4; j++) acc[i][j] = fmaf(a8[i], b4[j], acc[i][j]);
    }
    __syncthreads();
  }
  float bv4[4] = {0.f, 0.f, 0.f, 0.f};
  if (bias) {
#pragma unroll
    for (int j = 0; j < 4; j++) bv4[j] = inF(bias, (size_t)(n0 + tn * 4 + j), bf);
  }
#pragma unroll
  for (int i = 0; i < 8; i++) {
#pragma unroll
    for (int j = 0; j < 4; j++) {
      float v = acc[i][j] + bv4[j];
      if (act == 1) v = tanhf(v);
      size_t ci = strideC * bz + (m0 + tm * 8 + i) * (size_t)ldc + (n0 + tn * 4 + j);
      if (cF32) ((float*)C)[ci] = v;
      else ((u16*)C)[ci] = f2b(v);
    }
  }
}

// NN variant (B[k][n], used for mix = w @ enc)
__global__ __launch_bounds__(256) void k_gemm_nn(
    const u16* __restrict__ A0, int K,
    const void* __restrict__ B, size_t strideB, int ldb,
    void* __restrict__ C, size_t strideC, int ldc,
    size_t strideA, const int* __restrict__ flagp) {
  const int bf = flagp[0];
  __shared__ float a_s[BK][BM + 4];
  __shared__ float b_s[BK][BN + 4];
  const int tid = threadIdx.x;
  const size_t m0 = (size_t)blockIdx.x * BM;
  const int n0 = blockIdx.y * BN;
  const size_t bz = blockIdx.z;
  const int tm = tid & 15, tn = tid >> 4;
  const int arow = tid >> 1, ak8 = (tid & 1) << 3;
  const int bkr = tid >> 4, bn4 = (tid & 15) << 2;
  float acc[8][4];
#pragma unroll
  for (int i = 0; i < 8; i++)
#pragma unroll
    for (int j = 0; j < 4; j++) acc[i][j] = 0.f;

  for (int k0 = 0; k0 < K; k0 += BK) {
    {
      const u16* ap = A0 + strideA * bz + (m0 + arow) * (size_t)K + (k0 + ak8);
      ushort4 u0 = reinterpret_cast<const ushort4*>(ap)[0];
      ushort4 u1 = reinterpret_cast<const ushort4*>(ap)[1];
      a_s[ak8 + 0][arow] = b2f(u0.x); a_s[ak8 + 1][arow] = b2f(u0.y);
      a_s[ak8 + 2][arow] = b2f(u0.z); a_s[ak8 + 3][arow] = b2f(u0.w);
      a_s[ak8 + 4][arow] = b2f(u1.x); a_s[ak8 + 5][arow] = b2f(u1.y);
      a_s[ak8 + 6][arow] = b2f(u1.z); a_s[ak8 + 7][arow] = b2f(u1.w);
    }
    {
      float v[4];
      inF4(B, strideB * bz + (size_t)(k0 + bkr) * ldb + (n0 + bn4), bf, v);
      *reinterpret_cast<float4*>(&b_s[bkr][bn4]) = make_float4(v[0], v[1], v[2], v[3]);
    }
    __syncthreads();
#pragma unroll
    for (int k = 0; k < BK; k++) {
      const float4 av0 = *reinterpret_cast<const float4*>(&a_s[k][tm * 8]);
      const float4 av1 = *reinterpret_cast<const float4*>(&a_s[k][tm * 8 + 4]);
      const float4 bv = *reinterpret_cast<const float4*>(&b_s[k][tn * 4]);
      const float a8[8] = {av0.x, av0.y, av0.z, av0.w, av1.x, av1.y, av1.z, av1.w};
      const float b4[4] = {bv.x, bv.y, bv.z, bv.w};
#pragma unroll
      for (int i = 0; i < 8; i++)
#pragma unroll
        for (int j = 0; j < 4; j++) acc[i][j] = fmaf(a8[i], b4[j], acc[i][j]);
    }
    __syncthreads();
  }
#pragma unroll
  for (int i = 0; i < 8; i++) {
#pragma unroll
    for (int j = 0; j < 4; j++) {
      size_t ci = strideC * bz + (m0 + tm * 8 + i) * (size_t)ldc + (n0 + tn * 4 + j);
      ((u16*)C)[ci] = f2b(acc[i][j]);
    }
  }
}

// ---------------- masked softmax over T_ENC (in-place on bf16 scores) ----------------
__global__ __launch_bounds__(256) void k_softmax(
    u16* __restrict__ S, const int* __restrict__ lens) {
  const int m = blockIdx.x;       // b*512 + t
  const int b = m >> 9;
  const int len = lens[b];
  const int tid = threadIdx.x;
  const size_t base = (size_t)m * TENC;
  float v[4];
  float mx = -1e30f;
#pragma unroll
  for (int i = 0; i < 4; i++) {
    int j = tid + i * 256;
    float s = b2f(S[base + j]);
    v[i] = (j < len) ? s : -1e30f;
    mx = fmaxf(mx, v[i]);
  }
  __shared__ float red[8];
  for (int o = 32; o; o >>= 1) mx = fmaxf(mx, __shfl_xor(mx, o, 64));
  if ((tid & 63) == 0) red[tid >> 6] = mx;
  __syncthreads();
  mx = fmaxf(fmaxf(red[0], red[1]), fmaxf(red[2], red[3]));
  float e[4]; float sum = 0.f;
#pragma unroll
  for (int i = 0; i < 4; i++) {
    e[i] = (v[i] > -1e29f) ? expf(v[i] - mx) : 0.f;
    sum += e[i];
  }
  for (int o = 32; o; o >>= 1) sum += __shfl_xor(sum, o, 64);
  __shared__ float red2[8];
  if ((tid & 63) == 0) red2[tid >> 6] = sum;
  __syncthreads();
  sum = red2[0] + red2[1] + red2[2] + red2[3];
  const float inv = 1.f / sum;
#pragma unroll
  for (int i = 0; i < 4; i++) S[base + tid + i * 256] = f2b(e[i] * inv);
}

// ---------------- one GRU time step ----------------
// grid 256 blocks (4 features each), 512 threads = 32 b x 4 jj x 4 kh
__global__ __launch_bounds__(512) void k_gru_step(
    const float* __restrict__ hcur, float* __restrict__ hnext,
    const void* __restrict__ w_hh, const void* __restrict__ b_hh,
    const u16* __restrict__ xp, u16* __restrict__ y,
    int t, const int* __restrict__ flagp) {
  const int bf = flagp[0];
  __shared__ u16 h_lds[32][1026];
  __shared__ float p_lds[4][4][3][32];  // [kh][jj][gate][b]
  const int tid = threadIdx.x;
  // stage h (f32 global -> bf16 LDS)
  for (int i = tid; i < 8192; i += 512) {
    float4 hv = reinterpret_cast<const float4*>(hcur)[i];
    int e = i << 2; int br = e >> 10; int k = e & 1023;
    u32 lo = (u32)f2b(hv.x) | ((u32)f2b(hv.y) << 16);
    u32 hi = (u32)f2b(hv.z) | ((u32)f2b(hv.w) << 16);
    *reinterpret_cast<u32*>(&h_lds[br][k]) = lo;
    *reinterpret_cast<u32*>(&h_lds[br][k + 2]) = hi;
  }
  __syncthreads();
  const int b = tid & 31, q = tid >> 5;
  const int jj = q & 3, kh = q >> 2;
  const int g = blockIdx.x * 4 + jj;
  const int k0 = kh << 8;
  const size_t wr0 = (size_t)g * HD;
  const size_t wz0 = (size_t)(HD + g) * HD;
  const size_t wn0 = (size_t)(2 * HD + g) * HD;
  float ar = 0.f, az = 0.f, an = 0.f;
#pragma unroll 4
  for (int k = k0; k < k0 + 256; k += 4) {
    u32 p0 = *reinterpret_cast<const u32*>(&h_lds[b][k]);
    u32 p1 = *reinterpret_cast<const u32*>(&h_lds[b][k + 2]);
    float h0 = b2f((u16)p0), h1 = b2f((u16)(p0 >> 16));
    float h2 = b2f((u16)p1), h3 = b2f((u16)(p1 >> 16));
    float wr[4], wz[4], wn[4];
    inF4(w_hh, wr0 + k, bf, wr);
    inF4(w_hh, wz0 + k, bf, wz);
    inF4(w_hh, wn0 + k, bf, wn);
    ar = fmaf(h0, wr[0], fmaf(h1, wr[1], fmaf(h2, wr[2], fmaf(h3, wr[3], ar))));
    az = fmaf(h0, wz[0], fmaf(h1, wz[1], fmaf(h2, wz[2], fmaf(h3, wz[3], az))));
    an = fmaf(h0, wn[0], fmaf(h1, wn[1], fmaf(h2, wn[2], fmaf(h3, wn[3], an))));
  }
  p_lds[kh][jj][0][b] = ar;
  p_lds[kh][jj][1][b] = az;
  p_lds[kh][jj][2][b] = an;
  __syncthreads();
  if (kh == 0) {
    float R = p_lds[0][jj][0][b] + p_lds[1][jj][0][b] + p_lds[2][jj][0][b] + p_lds[3][jj][0][b]
              + inF(b_hh, (size_t)g, bf);
    float Z = p_lds[0][jj][1][b] + p_lds[1][jj][1][b] + p_lds[2][jj][1][b] + p_lds[3][jj][1][b]
              + inF(b_hh, (size_t)(HD + g), bf);
    float N = p_lds[0][jj][2][b] + p_lds[1][jj][2][b] + p_lds[2][jj][2][b] + p_lds[3][jj][2][b]
              + inF(b_hh, (size_t)(2 * HD + g), bf);
    const size_t m = ((size_t)b << 9) + t;
    float xr = b2f(xp[m * G3 + g]);
    float xz = b2f(xp[m * G3 + HD + g]);
    float xn = b2f(xp[m * G3 + 2 * HD + g]);
    float r = 1.f / (1.f + expf(-(xr + R)));
    float z = 1.f / (1.f + expf(-(xz + Z)));
    float n = tanhf(xn + r * N);
    float hp = hcur[(size_t)b * HD + g];
    float hv = (1.f - z) * n + z * hp;
    hnext[(size_t)b * HD + g] = hv;
    y[m * HD + g] = f2b(hv);
  }
}

// ---------------- log_softmax over V (f32 logits -> flag-dtype out) ----------------
__global__ __launch_bounds__(256) void k_logsoftmax(
    const float* __restrict__ L, void* __restrict__ out, const int* __restrict__ flagp) {
  const int bf = flagp[0];
  const int m = blockIdx.x;
  const int tid = threadIdx.x;
  const size_t base = (size_t)m * VOC;
  float v0 = L[base + tid], v1 = L[base + tid + 256];
  float mx = fmaxf(v0, v1);
  __shared__ float red[8];
  for (int o = 32; o; o >>= 1) mx = fmaxf(mx, __shfl_xor(mx, o, 64));
  if ((tid & 63) == 0) red[tid >> 6] = mx;
  __syncthreads();
  mx = fmaxf(fmaxf(red[0], red[1]), fmaxf(red[2], red[3]));
  float s = expf(v0 - mx) + expf(v1 - mx);
  for (int o = 32; o; o >>= 1) s += __shfl_xor(s, o, 64);
  __shared__ float red2[8];
  if ((tid & 63) == 0) red2[tid >> 6] = s;
  __syncthreads();
  s = red2[0] + red2[1] + red2[2] + red2[3];
  const float lse = mx + logf(s);
  outF(out, base + tid, v0 - lse, bf);
  outF(out, base + tid + 256, v1 - lse, bf);
}

extern "C" void kernel_launch(void* const* d_in, const int* in_sizes, int n_in,
                              void* d_out, int out_size, void* d_ws, size_t ws_size,
                              hipStream_t stream) {
  const void* enc = d_in[0];
  const int* lens = (const int*)d_in[1];
  const int* labels = (const int*)d_in[2];
  const void* emb = d_in[3];
  const void* lin_in = d_in[4];
  const void* lin_out = d_in[5];
  const void* w_ih0 = d_in[6];
  const void* w_hh0 = d_in[7];
  const void* b_ih0 = d_in[8];
  const void* b_hh0 = d_in[9];
  const void* w_ih1 = d_in[10];
  const void* w_hh1 = d_in[11];
  const void* b_ih1 = d_in[12];
  const void* b_hh1 = d_in[13];
  const void* fc_w = d_in[14];
  const void* fc_b = d_in[15];

  char* ws = (char*)d_ws;
  size_t off = 0;
  auto take = [&](size_t bytes) -> char* {
    char* p = ws + off;
    off = (off + bytes + 255) & ~(size_t)255;
    return p;
  };
  int* flag = (int*)take(256);
  float* hA = (float*)take(NB * HD * 4);
  float* hB = (float*)take(NB * HD * 4);
  const size_t SZ = (size_t)NB * TSEQ * HD * 2;  // 33.5 MB bf16
  u16* bufA = (u16*)take(SZ);          // x -> attn_out -> y1
  u16* bufB = (u16*)take(SZ);          // q -> y0
  u16* bufC = (u16*)take(SZ);          // scores/w (bf16) -> logits (f32, same bytes)
  u16* bufD = (u16*)take(SZ);          // mix
  u16* bufE = (u16*)take((size_t)NB * TSEQ * G3 * 2);  // xp0/xp1

  k_detect<<<1, 256, 0, stream>>>((const u32*)emb, flag);
  // x = emb[labels-with-SOS]
  k_embed<<<NB * TSEQ, 256, 0, stream>>>(labels, emb, bufA, flag);
  // q = x @ lin_in^T
  k_gemm_nt<<<dim3(128, 16, 1), 256, 0, stream>>>(bufA, nullptr, HD, HD, lin_in, 0, nullptr,
                                                  bufB, 0, 0, HD, 0, 0, flag);
  // scores[b] = q[b] @ enc[b]^T
  k_gemm_nt<<<dim3(4, 16, NB), 256, 0, stream>>>(bufB, nullptr, HD, HD, enc,
                                                 (size_t)TENC * HD, nullptr, bufC, 0,
                                                 (size_t)TSEQ * TENC, TENC,
                                                 (size_t)TSEQ * HD, 0, flag);
  // masked softmax (in place)
  k_softmax<<<NB * TSEQ, 256, 0, stream>>>(bufC, lens);
  // mix[b] = w[b] @ enc[b]
  k_gemm_nn<<<dim3(4, 16, NB), 256, 0, stream>>>(bufC, TENC, enc, (size_t)TENC * HD, HD,
                                                 bufD, (size_t)TSEQ * HD, HD,
                                                 (size_t)TSEQ * TENC, flag);
  // attn_out = tanh([mix|q] @ lin_out^T)
  k_gemm_nt<<<dim3(128, 16, 1), 256, 0, stream>>>(bufD, bufB, HD, 2 * HD, lin_out, 0, nullptr,
                                                  bufA, 0, 0, HD, 0, 1, flag);
  // xp0 = attn_out @ w_ih0^T + b_ih0
  k_gemm_nt<<<dim3(128, 48, 1), 256, 0, stream>>>(bufA, nullptr, HD, HD, w_ih0, 0, b_ih0,
                                                  bufE, 0, 0, G3, 0, 0, flag);
  // GRU layer 0 -> y0 in bufB
  hipMemsetAsync(hA, 0, NB * HD * 4, stream);
  for (int t = 0; t < TSEQ; ++t) {
    const float* hc = (t & 1) ? hB : hA;
    float* hn = (t & 1) ? hA : hB;
    k_gru_step<<<256, 512, 0, stream>>>(hc, hn, w_hh0, b_hh0, bufE, bufB, t, flag);
  }
  // xp1 = y0 @ w_ih1^T + b_ih1
  k_gemm_nt<<<dim3(128, 48, 1), 256, 0, stream>>>(bufB, nullptr, HD, HD, w_ih1, 0, b_ih1,
                                                  bufE, 0, 0, G3, 0, 0, flag);
  // GRU layer 1 -> y1 in bufA
  hipMemsetAsync(hA, 0, NB * HD * 4, stream);
  for (int t = 0; t < TSEQ; ++t) {
    const float* hc = (t & 1) ? hB : hA;
    float* hn = (t & 1) ? hA : hB;
    k_gru_step<<<256, 512, 0, stream>>>(hc, hn, w_hh1, b_hh1, bufE, bufA, t, flag);
  }
  // logits (f32) = y1 @ fc_w^T + fc_b  -> bufC reinterpreted as f32
  k_gemm_nt<<<dim3(128, 8, 1), 256, 0, stream>>>(bufA, nullptr, HD, HD, fc_w, 0, fc_b,
                                                 (void*)bufC, 1, 0, VOC, 0, 0, flag);
  // log_softmax -> d_out
  k_logsoftmax<<<NB * TSEQ, 256, 0, stream>>>((const float*)bufC, d_out, flag);
}

// Round 2
// 8175.867 us; speedup vs baseline: 2.6843x; 2.6843x over previous
//
#include <hip/hip_runtime.h>

typedef unsigned short u16;
typedef unsigned int u32;
typedef short bs8 __attribute__((ext_vector_type(8)));
typedef float f4_t __attribute__((ext_vector_type(4)));

#define NB   32
#define TSEQ 512
#define TENC 1024
#define HD   1024
#define VOC  512

#define AS1 __attribute__((address_space(1)))
#define AS3 __attribute__((address_space(3)))

__device__ __forceinline__ float b2f(u16 u) {
  union { u32 i; float f; } x; x.i = ((u32)u) << 16; return x.f;
}
__device__ __forceinline__ u16 f2b(float f) {
  union { float ff; u32 i; } x; x.ff = f;
  u32 r = x.i + 0x7fff + ((x.i >> 16) & 1);   // RNE
  return (u16)(r >> 16);
}
__device__ __forceinline__ float inF(const void* p, size_t i, int bf) {
  return bf ? b2f(((const u16*)p)[i]) : ((const float*)p)[i];
}
__device__ __forceinline__ void inF4(const void* p, size_t i, int bf, float* o) {
  if (bf) {
    ushort4 u = *reinterpret_cast<const ushort4*>((const u16*)p + i);
    o[0] = b2f(u.x); o[1] = b2f(u.y); o[2] = b2f(u.z); o[3] = b2f(u.w);
  } else {
    float4 v = *reinterpret_cast<const float4*>((const float*)p + i);
    o[0] = v.x; o[1] = v.y; o[2] = v.z; o[3] = v.w;
  }
}
__device__ __forceinline__ void outF(void* p, size_t i, float v, int bf) {
  if (bf) ((u16*)p)[i] = f2b(v);
  else ((float*)p)[i] = v;
}
__device__ __forceinline__ void gld16(const void* g, void* l) {
  __builtin_amdgcn_global_load_lds((const AS1 u32*)g, (AS3 u32*)l, 16, 0, 0);
}

// ---------------- dtype detect ----------------
__global__ void k_detect(const u32* __restrict__ w, int* __restrict__ flag) {
  __shared__ int cnt;
  if (threadIdx.x == 0) cnt = 0;
  __syncthreads();
  int c = 0;
  for (int i = threadIdx.x; i < 1024; i += 256) {
    u32 e = (w[i] >> 7) & 0xFF;
    if (e >= 100 && e <= 126) c++;
  }
  atomicAdd(&cnt, c);
  __syncthreads();
  if (threadIdx.x == 0) flag[0] = (cnt >= 512) ? 1 : 0;
}

// ---------------- generic f32|bf16 -> bf16 convert ----------------
__global__ __launch_bounds__(256) void k_f2bf(
    const void* __restrict__ in, u16* __restrict__ out, const int* __restrict__ flagp) {
  const int bf = flagp[0];
  size_t i = ((size_t)blockIdx.x * 256 + threadIdx.x) * 4;
  float v[4]; inF4(in, i, bf, v);
  ushort4 o; o.x = f2b(v[0]); o.y = f2b(v[1]); o.z = f2b(v[2]); o.w = f2b(v[3]);
  *reinterpret_cast<ushort4*>(&out[i]) = o;
}

// ---------------- embedding gather (with SOS prepend) -> bf16 x ----------------
__global__ __launch_bounds__(256) void k_embed(
    const int* __restrict__ labels, const void* __restrict__ emb,
    u16* __restrict__ x, const int* __restrict__ flagp) {
  const int bf = flagp[0];
  const int m = blockIdx.x;            // m = b*512 + t
  const int b = m >> 9, t = m & 511;
  const int lab = (t == 0) ? 0 : labels[b * 511 + t - 1];
  const size_t src = (size_t)lab * HD;
  const size_t dst = (size_t)m * HD;
  const int k = threadIdx.x * 4;
  float v[4]; inF4(emb, src + k, bf, v);
  ushort4 o; o.x = f2b(v[0]); o.y = f2b(v[1]); o.z = f2b(v[2]); o.w = f2b(v[3]);
  *reinterpret_cast<ushort4*>(&x[dst + k]) = o;
}

// ---------------- enc transpose: [b][t][h] f32|bf16 -> [b][h][t] bf16 ----------------
__global__ __launch_bounds__(256) void k_transpose(
    const void* __restrict__ enc, u16* __restrict__ encT, const int* __restrict__ flagp) {
  const int bf = flagp[0];
  __shared__ float tile[32][33];
  const int b = blockIdx.z, t0 = blockIdx.x * 32, h0 = blockIdx.y * 32;
  const int i = threadIdx.x >> 5, j = threadIdx.x & 31;
  const size_t base = (size_t)b * (TENC * HD);
#pragma unroll
  for (int rr = 0; rr < 4; rr++) {
    int r = i + rr * 8;
    tile[r][j] = inF(enc, base + (size_t)(t0 + r) * HD + h0 + j, bf);
  }
  __syncthreads();
#pragma unroll
  for (int rr = 0; rr < 4; rr++) {
    int r = i + rr * 8;
    encT[base + (size_t)(h0 + r) * TENC + t0 + j] = f2b(tile[j][r]);
  }
}

// ---------------- MFMA GEMM: C[m][n] = act(sum_k A[m][k]*B[n][k] + bias[n]) ----------------
// A,B bf16 row-major (lda/ldb = K-stride). 128x128 tile, BK=64, 4 waves, 16x16x32 MFMA.
// cmode: 0 = bf16 row-major, 1 = f32 row-major, 2 = swizzled per-t layout (attn_swz)
__global__ __launch_bounds__(256) void k_mfma_gemm(
    const u16* __restrict__ A, const u16* __restrict__ Bm, int K, int lda, int ldb,
    long strideA, long strideB, long strideC,
    void* __restrict__ C, int ldc, int cmode, int act,
    const void* __restrict__ bias, const int* __restrict__ flagp) {
  const int bf = flagp[0];
  __shared__ u16 lsA[8192];   // [128 rows][64 k] bf16, 128B rows, XOR-swizzled image
  __shared__ u16 lsB[8192];
  const int tid = threadIdx.x;
  const int l = tid & 63, w = tid >> 6;
  const int wr = w >> 1, wc = w & 1;
  const long m0 = (long)blockIdx.x * 128;
  const long n0 = (long)blockIdx.y * 128;
  const long bz = blockIdx.z;
  const u16* Ab = A + bz * strideA;
  const u16* Bb = Bm + bz * strideB;

  f4_t acc[4][4] = {};
  const int srow = w * 8 + (l >> 3);       // + i*32
  const int schx = (l & 7) * 16;           // byte chunk within 128B window

  for (int kt = 0; kt < K; kt += 64) {
#pragma unroll
    for (int i = 0; i < 4; i++) {
      const int row = i * 32 + srow;
      const char* ga = (const char*)(Ab + (m0 + row) * (long)lda + kt)
                       + (schx ^ ((row & 7) << 4));
      gld16(ga, (char*)lsA + i * 4096 + w * 1024);
    }
#pragma unroll
    for (int i = 0; i < 4; i++) {
      const int row = i * 32 + srow;
      const char* gb = (const char*)(Bb + (n0 + row) * (long)ldb + kt)
                       + (schx ^ ((row & 7) << 4));
      gld16(gb, (char*)lsB + i * 4096 + w * 1024);
    }
    __syncthreads();
#pragma unroll
    for (int h = 0; h < 2; h++) {
      bs8 af[4], bfr[4];
#pragma unroll
      for (int i = 0; i < 4; i++) {
        const int row = wr * 64 + i * 16 + (l & 15);
        const int byt = row * 128 + (((h * 64) + ((l >> 4) * 16)) ^ ((row & 7) << 4));
        af[i] = *(const bs8*)((const char*)lsA + byt);
      }
#pragma unroll
      for (int j = 0; j < 4; j++) {
        const int row = wc * 64 + j * 16 + (l & 15);
        const int byt = row * 128 + (((h * 64) + ((l >> 4) * 16)) ^ ((row & 7) << 4));
        bfr[j] = *(const bs8*)((const char*)lsB + byt);
      }
#pragma unroll
      for (int i = 0; i < 4; i++)
#pragma unroll
        for (int j = 0; j < 4; j++)
          acc[i][j] = __builtin_amdgcn_mfma_f32_16x16x32_bf16(af[i], bfr[j], acc[i][j], 0, 0, 0);
    }
    __syncthreads();
  }

  // epilogue: C/D layout col=lane&15, row=(lane>>4)*4+reg  [m89-verified]
  float bv[4] = {0.f, 0.f, 0.f, 0.f};
  if (bias) {
#pragma unroll
    for (int j = 0; j < 4; j++)
      bv[j] = inF(bias, (size_t)(n0 + wc * 64 + j * 16 + (l & 15)), bf);
  }
#pragma unroll
  for (int i = 0; i < 4; i++) {
#pragma unroll
    for (int j = 0; j < 4; j++) {
      const long rowb = m0 + wr * 64 + i * 16 + ((l >> 4) * 4);
      const long col = n0 + wc * 64 + j * 16 + (l & 15);
#pragma unroll
      for (int r = 0; r < 4; r++) {
        float v = acc[i][j][r] + bv[j];
        if (act == 1) v = tanhf(v);
        const long row = rowb + r;
        if (cmode == 0) {
          ((u16*)C)[bz * strideC + row * (long)ldc + col] = f2b(v);
        } else if (cmode == 1) {
          ((float*)C)[bz * strideC + row * (long)ldc + col] = v;
        } else {
          const long b = row >> 9, t = row & 511;
          const long byt = t * 65536 + b * 2048 + (((long)(col * 2)) ^ ((b & 7) << 4));
          ((u16*)C)[byt >> 1] = f2b(v);
        }
      }
    }
  }
}

// ---------------- masked softmax over T_ENC (in-place bf16) ----------------
__global__ __launch_bounds__(256) void k_softmax(
    u16* __restrict__ S, const int* __restrict__ lens) {
  const int m = blockIdx.x;
  const int b = m >> 9;
  const int len = lens[b];
  const int tid = threadIdx.x;
  const size_t base = (size_t)m * TENC;
  float v[4];
  float mx = -1e30f;
#pragma unroll
  for (int i = 0; i < 4; i++) {
    int j = tid + i * 256;
    float s = b2f(S[base + j]);
    v[i] = (j < len) ? s : -1e30f;
    mx = fmaxf(mx, v[i]);
  }
  __shared__ float red[8];
  for (int o = 32; o; o >>= 1) mx = fmaxf(mx, __shfl_xor(mx, o, 64));
  if ((tid & 63) == 0) red[tid >> 6] = mx;
  __syncthreads();
  mx = fmaxf(fmaxf(red[0], red[1]), fmaxf(red[2], red[3]));
  float e[4]; float sum = 0.f;
#pragma unroll
  for (int i = 0; i < 4; i++) {
    e[i] = (v[i] > -1e29f) ? expf(v[i] - mx) : 0.f;
    sum += e[i];
  }
  for (int o = 32; o; o >>= 1) sum += __shfl_xor(sum, o, 64);
  __shared__ float red2[8];
  if ((tid & 63) == 0) red2[tid >> 6] = sum;
  __syncthreads();
  sum = red2[0] + red2[1] + red2[2] + red2[3];
  const float inv = 1.f / sum;
#pragma unroll
  for (int i = 0; i < 4; i++) S[base + tid + i * 256] = f2b(e[i] * inv);
}

// ---------------- pack [w_ih | w_hh] into MFMA-frag order ----------------
// wpack[blk][ks(64)][lane(64)][8] bf16. col c=lane&15: 0-3=r, 4-7=z, 8-11=n_ih, 12-15=n_hh
__global__ __launch_bounds__(256) void k_pack_w(
    const void* __restrict__ w_ih, const void* __restrict__ w_hh,
    u16* __restrict__ wpack, const int* __restrict__ flagp) {
  const int bf = flagp[0];
  const long idx = (long)blockIdx.x * 256 + threadIdx.x;  // (blk*64+ks)*64+l
  const int l = idx & 63;
  const long t2 = idx >> 6;
  const int ks = t2 & 63;
  const int blk = (int)(t2 >> 6);
  const int c = l & 15, kg = l >> 4;
  const int gate = c >> 2, f = c & 3;
  const int g = blk * 4 + f;
  const int k = ks * 32 + kg * 8;
  const bool xpart = (k < 1024);
  const void* W = xpart ? w_ih : w_hh;
  const int kk = xpart ? k : k - 1024;
  long row; bool zero = false;
  if (gate == 0) row = g;
  else if (gate == 1) row = 1024 + g;
  else if (gate == 2) { row = 2048 + g; zero = !xpart; }
  else { row = 2048 + g; zero = xpart; }
  u16 o[8];
#pragma unroll
  for (int e = 0; e < 8; e++)
    o[e] = zero ? (u16)0 : f2b(inF(W, (size_t)row * 1024 + kk + e, bf));
  ushort4* dst = (ushort4*)(wpack + idx * 8);
  dst[0] = make_ushort4(o[0], o[1], o[2], o[3]);
  dst[1] = make_ushort4(o[4], o[5], o[6], o[7]);
}

// ---------------- fused GRU step (input-proj + recurrent, MFMA) ----------------
// A = [x_t(swz) ; h(swz)] 32 rows x 2048 k; B = wpack slice (16 cols); 4 waves k-split.
__global__ __launch_bounds__(256) void k_gru(
    const u16* __restrict__ xin_swz, const u16* __restrict__ h_swz_cur,
    u16* __restrict__ h_swz_nxt, float* __restrict__ h_f32,
    const u16* __restrict__ wpack,
    const void* __restrict__ b_ih, const void* __restrict__ b_hh,
    u16* __restrict__ yout, int ymode, int t, const int* __restrict__ flagp) {
  const int bf = flagp[0];
  __shared__ u16 hx[65536];      // 128KB: [0,64K)=x_t swz image, [64K,128K)=h swz image
  __shared__ float red[2048];    // 8KB: [w][mt][lane][4]
  const int tid = threadIdx.x;
  const int l = tid & 63, w = tid >> 6;

  {  // linear 64KB copies (both buffers already stored in swizzled byte order)
    const char* gx = (const char*)(xin_swz + (long)t * 32768);
#pragma unroll
    for (int i = 0; i < 16; i++) {
      const int off = i * 4096 + w * 1024;
      gld16(gx + off + l * 16, (char*)hx + off);
    }
    const char* gh = (const char*)h_swz_cur;
#pragma unroll
    for (int i = 0; i < 16; i++) {
      const int off = i * 4096 + w * 1024;
      gld16(gh + off + l * 16, (char*)hx + 65536 + off);
    }
  }
  __syncthreads();

  f4_t acc[2] = {};
  const u16* wp = wpack + (long)blockIdx.x * (64 * 64 * 8);
  for (int s = 0; s < 16; s++) {
    const int ks = w * 16 + s;
    const bs8 bfrag = *(const bs8*)(wp + ((long)ks * 64 + l) * 8);
#pragma unroll
    for (int mt = 0; mt < 2; mt++) {
      const int row = mt * 16 + (l & 15);
      const int x = (ks & 31) * 64 + ((l >> 4) * 16);
      const int byt = ((ks >= 32) ? 65536 : 0) + row * 2048 + (x ^ ((row & 7) << 4));
      const bs8 afrag = *(const bs8*)((const char*)hx + byt);
      acc[mt] = __builtin_amdgcn_mfma_f32_16x16x32_bf16(afrag, bfrag, acc[mt], 0, 0, 0);
    }
  }
#pragma unroll
  for (int mt = 0; mt < 2; mt++)
    *(f4_t*)&red[((w * 2 + mt) * 64 + l) * 4] = acc[mt];
  __syncthreads();

  if (tid < 128) {
    const int b = tid & 31, f = tid >> 5;
    const int g = blockIdx.x * 4 + f;
    const int mt = b >> 4, bl = b & 15, r = bl & 3;
    float gv[4];
#pragma unroll
    for (int c4 = 0; c4 < 4; c4++) {
      const int c = c4 * 4 + f;
      const int li = ((bl >> 2) << 4) | c;
      float s = 0.f;
#pragma unroll
      for (int ww = 0; ww < 4; ww++) s += red[((ww * 2 + mt) * 64 + li) * 4 + r];
      gv[c4] = s;
    }
    const float Rs = gv[0] + inF(b_ih, g, bf) + inF(b_hh, g, bf);
    const float Zs = gv[1] + inF(b_ih, 1024 + g, bf) + inF(b_hh, 1024 + g, bf);
    const float xn = gv[2] + inF(b_ih, 2048 + g, bf);
    const float hn = gv[3] + inF(b_hh, 2048 + g, bf);
    const float rr = 1.f / (1.f + expf(-Rs));
    const float zz = 1.f / (1.f + expf(-Zs));
    const float nn = tanhf(xn + rr * hn);
    const float hp = h_f32[b * 1024 + g];
    const float hv = (1.f - zz) * nn + zz * hp;
    h_f32[b * 1024 + g] = hv;
    const u16 hb = f2b(hv);
    const int swb = b * 2048 + ((2 * g) ^ ((b & 7) << 4));
    h_swz_nxt[swb >> 1] = hb;
    if (ymode == 0) {
      yout[((long)t * 65536 + swb) >> 1] = hb;          // swz-per-t (feeds next layer)
    } else {
      yout[((long)b * 512 + t) * 1024 + g] = hb;        // row-major (feeds logits GEMM)
    }
  }
}

// ---------------- log_softmax over V ----------------
__global__ __launch_bounds__(256) void k_logsoftmax(
    const float* __restrict__ L, void* __restrict__ out, const int* __restrict__ flagp) {
  const int bf = flagp[0];
  const int m = blockIdx.x;
  const int tid = threadIdx.x;
  const size_t base = (size_t)m * VOC;
  float v0 = L[base + tid], v1 = L[base + tid + 256];
  float mx = fmaxf(v0, v1);
  __shared__ float red[8];
  for (int o = 32; o; o >>= 1) mx = fmaxf(mx, __shfl_xor(mx, o, 64));
  if ((tid & 63) == 0) red[tid >> 6] = mx;
  __syncthreads();
  mx = fmaxf(fmaxf(red[0], red[1]), fmaxf(red[2], red[3]));
  float s = expf(v0 - mx) + expf(v1 - mx);
  for (int o = 32; o; o >>= 1) s += __shfl_xor(s, o, 64);
  __shared__ float red2[8];
  if ((tid & 63) == 0) red2[tid >> 6] = s;
  __syncthreads();
  s = red2[0] + red2[1] + red2[2] + red2[3];
  const float lse = mx + logf(s);
  outF(out, base + tid, v0 - lse, bf);
  outF(out, base + tid + 256, v1 - lse, bf);
}

extern "C" void kernel_launch(void* const* d_in, const int* in_sizes, int n_in,
                              void* d_out, int out_size, void* d_ws, size_t ws_size,
                              hipStream_t stream) {
  const void* enc = d_in[0];
  const int* lens = (const int*)d_in[1];
  const int* labels = (const int*)d_in[2];
  const void* emb = d_in[3];
  const void* lin_in = d_in[4];
  const void* lin_out = d_in[5];
  const void* w_ih0 = d_in[6];
  const void* w_hh0 = d_in[7];
  const void* b_ih0 = d_in[8];
  const void* b_hh0 = d_in[9];
  const void* w_ih1 = d_in[10];
  const void* w_hh1 = d_in[11];
  const void* b_ih1 = d_in[12];
  const void* b_hh1 = d_in[13];
  const void* fc_w = d_in[14];
  const void* fc_b = d_in[15];

  char* ws = (char*)d_ws;
  size_t off = 0;
  auto take = [&](size_t bytes) -> char* {
    char* p = ws + off;
    off = (off + bytes + 255) & ~(size_t)255;
    return p;
  };
  int* flag = (int*)take(256);
  float* h_f32 = (float*)take(NB * HD * 4);
  u16* hswz0 = (u16*)take(65536);
  u16* hswz1 = (u16*)take(65536);
  u16* wli = (u16*)take((size_t)HD * HD * 2);           // lin_in bf16
  u16* wlo = (u16*)take((size_t)HD * 2 * HD * 2);       // lin_out bf16
  u16* wfc = (u16*)take((size_t)VOC * HD * 2);          // fc_w bf16
  const size_t SZ = (size_t)NB * TSEQ * HD * 2;          // 33.5 MB
  u16* arena0 = (u16*)take(SZ);       // x -> encT -> y1
  u16* arena1 = (u16*)take(SZ);       // enc_bf -> y0_swz
  u16* arena2 = (u16*)take(2 * SZ);   // [mix|q] combined -> {logits f32 (lower) | wpack0/1 (upper)}
  u16* arena3 = (u16*)take(SZ);       // scores/w -> attn_swz
  u16* wp0 = arena2 + (SZ / 2) * 1;   // upper half of arena2, 16.8MB each
  u16* wp1 = wp0 + (size_t)256 * 64 * 64 * 8;

  u16* hs[2] = {hswz0, hswz1};

  k_detect<<<1, 256, 0, stream>>>((const u32*)emb, flag);
  k_embed<<<NB * TSEQ, 256, 0, stream>>>(labels, emb, arena0, flag);
  k_f2bf<<<32768, 256, 0, stream>>>(enc, arena1, flag);
  k_f2bf<<<1024, 256, 0, stream>>>(lin_in, wli, flag);
  k_f2bf<<<2048, 256, 0, stream>>>(lin_out, wlo, flag);
  k_f2bf<<<512, 256, 0, stream>>>(fc_w, wfc, flag);

  // q = x @ lin_in^T -> combined cols [1024,2048)
  k_mfma_gemm<<<dim3(128, 8, 1), 256, 0, stream>>>(
      arena0, wli, HD, HD, HD, 0, 0, 0, (void*)(arena2 + 1024), 2 * HD, 0, 0, nullptr, flag);
  // encT (x dead now)
  k_transpose<<<dim3(32, 32, NB), 256, 0, stream>>>(enc, arena0, flag);
  // scores[b] = q[b] @ enc_bf[b]^T
  k_mfma_gemm<<<dim3(4, 8, NB), 256, 0, stream>>>(
      arena2 + 1024, arena1, HD, 2 * HD, HD,
      (long)TSEQ * 2 * HD, (long)TENC * HD, (long)TSEQ * TENC,
      (void*)arena3, TENC, 0, 0, nullptr, flag);
  k_softmax<<<NB * TSEQ, 256, 0, stream>>>(arena3, lens);
  // mix[b] = w[b] @ encT[b]^T -> combined cols [0,1024)
  k_mfma_gemm<<<dim3(4, 8, NB), 256, 0, stream>>>(
      arena3, arena0, TENC, TENC, TENC,
      (long)TSEQ * TENC, (long)HD * TENC, (long)TSEQ * 2 * HD,
      (void*)arena2, 2 * HD, 0, 0, nullptr, flag);
  // attn = tanh(combined @ lin_out^T) -> attn_swz (cmode 2)
  k_mfma_gemm<<<dim3(128, 8, 1), 256, 0, stream>>>(
      arena2, wlo, 2 * HD, 2 * HD, 2 * HD, 0, 0, 0,
      (void*)arena3, 0, 2, 1, nullptr, flag);

  // pack GRU weights (into arena2 upper half — combined is dead now)
  k_pack_w<<<4096, 256, 0, stream>>>(w_ih0, w_hh0, wp0, flag);
  k_pack_w<<<4096, 256, 0, stream>>>(w_ih1, w_hh1, wp1, flag);

  // GRU layer 0: x = attn_swz -> y0_swz (arena1; enc_bf dead)
  hipMemsetAsync(h_f32, 0, NB * HD * 4, stream);
  hipMemsetAsync(hswz0, 0, 65536, stream);
  for (int t = 0; t < TSEQ; ++t)
    k_gru<<<256, 256, 0, stream>>>(arena3, hs[t & 1], hs[(t + 1) & 1], h_f32,
                                   wp0, b_ih0, b_hh0, arena1, 0, t, flag);
  // GRU layer 1: x = y0_swz -> y1 row-major (arena0; encT dead)
  hipMemsetAsync(h_f32, 0, NB * HD * 4, stream);
  hipMemsetAsync(hswz0, 0, 65536, stream);
  for (int t = 0; t < TSEQ; ++t)
    k_gru<<<256, 256, 0, stream>>>(arena1, hs[t & 1], hs[(t + 1) & 1], h_f32,
                                   wp1, b_ih1, b_hh1, arena0, 1, t, flag);

  // logits f32 = y1 @ fc_w^T + fc_b -> arena2 lower half
  k_mfma_gemm<<<dim3(128, 4, 1), 256, 0, stream>>>(
      arena0, wfc, HD, HD, HD, 0, 0, 0, (void*)arena2, VOC, 1, 0, fc_b, flag);
  k_logsoftmax<<<NB * TSEQ, 256, 0, stream>>>((const float*)arena2, d_out, flag);
}